// Round 8
// baseline (7000.562 us; speedup 1.0000x reference)
//
#include <hip/hip_runtime.h>
#include <math.h>

#define B_   64
#define T_   366
#define IN_  24
#define H1_  1024
#define H2_  2048
#define HM_  2048
#define G3_  (3 * HM_)
#define PEN_ 1024
#define C_   21
#define BT_  (B_ * T_)

#define TC_  61              // T-chunk length (366 = 6*61)
#define NCH  6
#define MC   (B_ * TC_)      // 3904 rows per chunk

typedef unsigned short bf16_t;
typedef __bf16 bf16x8 __attribute__((ext_vector_type(8)));
typedef float  f32x4  __attribute__((ext_vector_type(4)));

__device__ __forceinline__ float bf2f(bf16_t u) {
  return __uint_as_float(((unsigned int)u) << 16);
}
__device__ __forceinline__ bf16_t f2bf(float f) {
  unsigned int x = __float_as_uint(f);
  unsigned int r = (x + 0x7fffu + ((x >> 16) & 1u)) >> 16;
  return (bf16_t)r;
}

struct ushort4_t { bf16_t x, y, z, w; };

#define AS1 __attribute__((address_space(1)))
#define AS3 __attribute__((address_space(3)))

// ---------------------------------------------------------------------------
// MFMA bf16 GEMM: C = act(A@W^T+b).  (R2-proven, unchanged)
// ---------------------------------------------------------------------------
#define GBM 128
#define GBN 128
#define GBK 32
#define LDT 40

template<int WBF>
__global__ __launch_bounds__(256) void gemm_mfma(
    const bf16_t* __restrict__ A, const float* __restrict__ Wf,
    const bf16_t* __restrict__ Wb,
    const float* __restrict__ bias, bf16_t* __restrict__ C,
    int M, int N, int K, int relu)
{
  __shared__ bf16_t Asl[GBM * LDT];
  __shared__ bf16_t Wsl[GBN * LDT];
  const int tid  = threadIdx.x;
  const int m0   = blockIdx.x * GBM;
  const int n0   = blockIdx.y * GBN;
  const int wave = tid >> 6;
  const int lane = tid & 63;
  const int l16  = lane & 15;
  const int quad = lane >> 4;
  const int wm   = (wave & 1) * 64;
  const int wn   = (wave >> 1) * 64;

  f32x4 acc[4][4];
  #pragma unroll
  for (int i = 0; i < 4; ++i)
    #pragma unroll
    for (int j = 0; j < 4; ++j)
      acc[i][j] = (f32x4){0.f, 0.f, 0.f, 0.f};

  if (WBF) {
    const int r4 = lane >> 2;
    const int sg = (lane & 3) << 3;    // bf16 elems: 0,8,16,24
    for (int k0 = 0; k0 < K; k0 += GBK) {
      #pragma unroll
      for (int it = 0; it < 2; ++it) {
        const int row = wave * 32 + it * 16 + r4;
        const int ar  = (m0 + row < M) ? (m0 + row) : (M - 1);
        __builtin_amdgcn_global_load_lds(
            (const AS1 void*)(A + (size_t)ar * K + k0 + sg),
            (AS3 void*)&Asl[(wave * 2 + it) * 512], 16, 0, 0);
        __builtin_amdgcn_global_load_lds(
            (const AS1 void*)(Wb + (size_t)(n0 + row) * K + k0 + sg),
            (AS3 void*)&Wsl[(wave * 2 + it) * 512], 16, 0, 0);
      }
      __syncthreads();
      bf16x8 af[4], bfr[4];
      #pragma unroll
      for (int i = 0; i < 4; ++i)
        af[i] = *(const bf16x8*)&Asl[(wm + 16 * i + l16) * 32 + quad * 8];
      #pragma unroll
      for (int j = 0; j < 4; ++j)
        bfr[j] = *(const bf16x8*)&Wsl[(wn + 16 * j + l16) * 32 + quad * 8];
      #pragma unroll
      for (int i = 0; i < 4; ++i)
        #pragma unroll
        for (int j = 0; j < 4; ++j)
          acc[i][j] = __builtin_amdgcn_mfma_f32_16x16x32_bf16(af[i], bfr[j], acc[i][j], 0, 0, 0);
      __syncthreads();
    }
  } else {
    const int srow = tid >> 1;
    const int sseg = (tid & 1) << 4;
    const int arow = (m0 + srow < M) ? (m0 + srow) : (M - 1);
    for (int k0 = 0; k0 < K; k0 += GBK) {
      {
        const bf16_t* ga = A + (size_t)arow * K + k0 + sseg;
        const uint4 a0 = *(const uint4*)ga;
        const uint4 a1 = *(const uint4*)(ga + 8);
        *(uint4*)&Asl[srow * LDT + sseg]     = a0;
        *(uint4*)&Asl[srow * LDT + sseg + 8] = a1;
        const float* gw = Wf + (size_t)(n0 + srow) * K + k0 + sseg;
        const float4 w0 = *(const float4*)gw;
        const float4 w1 = *(const float4*)(gw + 4);
        const float4 w2 = *(const float4*)(gw + 8);
        const float4 w3 = *(const float4*)(gw + 12);
        ushort4_t p0 = {f2bf(w0.x), f2bf(w0.y), f2bf(w0.z), f2bf(w0.w)};
        ushort4_t p1 = {f2bf(w1.x), f2bf(w1.y), f2bf(w1.z), f2bf(w1.w)};
        ushort4_t p2 = {f2bf(w2.x), f2bf(w2.y), f2bf(w2.z), f2bf(w2.w)};
        ushort4_t p3 = {f2bf(w3.x), f2bf(w3.y), f2bf(w3.z), f2bf(w3.w)};
        *(ushort4_t*)&Wsl[srow * LDT + sseg]      = p0;
        *(ushort4_t*)&Wsl[srow * LDT + sseg + 4]  = p1;
        *(ushort4_t*)&Wsl[srow * LDT + sseg + 8]  = p2;
        *(ushort4_t*)&Wsl[srow * LDT + sseg + 12] = p3;
      }
      __syncthreads();
      bf16x8 af[4], bfr[4];
      #pragma unroll
      for (int i = 0; i < 4; ++i)
        af[i] = *(const bf16x8*)&Asl[(wm + 16 * i + l16) * LDT + quad * 8];
      #pragma unroll
      for (int j = 0; j < 4; ++j)
        bfr[j] = *(const bf16x8*)&Wsl[(wn + 16 * j + l16) * LDT + quad * 8];
      #pragma unroll
      for (int i = 0; i < 4; ++i)
        #pragma unroll
        for (int j = 0; j < 4; ++j)
          acc[i][j] = __builtin_amdgcn_mfma_f32_16x16x32_bf16(af[i], bfr[j], acc[i][j], 0, 0, 0);
      __syncthreads();
    }
  }

  #pragma unroll
  for (int j = 0; j < 4; ++j) {
    const int n = n0 + wn + 16 * j + l16;
    const float bn = bias[n];
    #pragma unroll
    for (int i = 0; i < 4; ++i) {
      #pragma unroll
      for (int reg = 0; reg < 4; ++reg) {
        const int m = m0 + wm + 16 * i + quad * 4 + reg;
        if (m < M) {
          float v = acc[i][j][reg] + bn;
          if (relu) v = fmaxf(v, 0.f);
          C[(size_t)m * N + n] = f2bf(v);
        }
      }
    }
  }
}

// ---------------------------------------------------------------------------
// GRU step v7 — R6-proven skeleton with 2 WGS PER CU (the one untested
// lever): 512 wgs x 512 thr, each wg owns 4 j-cols x 3 gates (12-row gate-
// packed B tile -> 1 MFMA per (wave,s)). LDS 21.9KB/wg so two wgs co-reside
// per CU: two independent barrier domains interleave, hiding the per-phase
// stage/barrier stalls that bound R1-R6 (all of which ran 1 wg/CU).
// Staging maps / fragment indices / reduce / epilogue = R6-verified patterns
// restricted to 4 columns. Persistent/coop path removed (R7 hang).
// ---------------------------------------------------------------------------
#define HLD 72   // padded LDS stride for 64-k tiles

__global__ __launch_bounds__(512) void gru_step(
    const bf16_t* __restrict__ h_bf_in, float* __restrict__ h_f,
    const bf16_t* __restrict__ Whh_bf, const bf16_t* __restrict__ xg_c,
    const float* __restrict__ b_hh,
    bf16_t* __restrict__ h_bf_out, bf16_t* __restrict__ hs_c, int tt)
{
  // hst: 2 teams x 64 x HLD x 2B = 18,432 B ; wst: 2 x 12 x HLD x 2B = 3,456 B
  // overlays after K-loop: red 4x64x4 f32 = 4,096 B (on hst);
  //                        sm_g 12x64 f32 = 3,072 B (on wst)
  __shared__ char smem[21888];
  bf16_t* hst = (bf16_t*)smem;
  bf16_t* wst = (bf16_t*)(smem + 18432);
  float*  red = (float*)smem;
  float*  sm_g = (float*)(smem + 18432);

  const int tid  = threadIdx.x;
  const int team = tid >> 8;           // K-half
  const int ttid = tid & 255;
  const int w4   = (tid >> 6) & 3;     // wave within team (= row-tile owner)
  const int lane = tid & 63;
  const int l16  = lane & 15;
  const int quad = lane >> 4;
  const int j0   = blockIdx.x * 4;
  const int kbase = team * (HM_ / 2);

  f32x4 acc0 = (f32x4){0.f, 0.f, 0.f, 0.f};  // cols: r=g*4+jc (12 used)

  // h staging: 64 rows, 4 thr/row, 32 B each (R6-proven mapping)
  const int hrow = ttid >> 2;
  const int hseg = (ttid & 3) << 4;
  // W staging: 12 rows (g*4+jc), 8 thr/row, 16 B each (valid ttid<96)
  const int wrow = ttid >> 3;          // 0..11
  const int wgi  = wrow >> 2;          // gate
  const int wjr  = wrow & 3;
  const int wseg = (ttid & 7) << 3;    // elems 0..56

  const bf16_t* gh_base = h_bf_in + (size_t)hrow * HM_ + kbase + hseg;
  const bf16_t* gw_base = Whh_bf + (size_t)(wgi * HM_ + j0 + wjr) * HM_ + kbase + wseg;

  // epilogue operand prefetch — tid<256, one (j,b) pair each (R6 pattern)
  const int ej  = tid & 3;
  const int eb  = (tid & 255) >> 2;    // 0..63
  const int jje = j0 + ej;
  bf16_t xrb = 0, xzb = 0, xnb = 0;
  float  hp = 0.f, bh_r = 0.f, bh_z = 0.f, bh_n = 0.f;
  if (tid < 256) {
    const size_t xrow = (size_t)(eb * TC_ + tt) * G3_;
    xrb = xg_c[xrow + jje];
    xzb = xg_c[xrow + HM_ + jje];
    xnb = xg_c[xrow + 2 * HM_ + jje];
    hp  = h_f[eb * HM_ + jje];
    bh_r = b_hh[jje];
    bh_z = b_hh[HM_ + jje];
    bh_n = b_hh[2 * HM_ + jje];
  }

  // preload k-tile 0
  uint4 h0 = *(const uint4*)(gh_base);
  uint4 h1 = *(const uint4*)(gh_base + 8);
  uint4 w0 = {0u,0u,0u,0u};
  if (ttid < 96) w0 = *(const uint4*)(gw_base);

  bf16_t* hT = hst + team * (64 * HLD);
  bf16_t* wT = wst + team * (12 * HLD);
  const int brow = (l16 < 12) ? l16 : 8;   // in-bounds dummy for unused cols

  for (int k0 = 0; k0 < HM_ / 2; k0 += 64) {
    *(uint4*)&hT[hrow * HLD + hseg]     = h0;
    *(uint4*)&hT[hrow * HLD + hseg + 8] = h1;
    if (ttid < 96) *(uint4*)&wT[wrow * HLD + wseg] = w0;
    __syncthreads();
    if (k0 + 64 < HM_ / 2) {
      h0 = *(const uint4*)(gh_base + k0 + 64);
      h1 = *(const uint4*)(gh_base + k0 + 64 + 8);
      if (ttid < 96) w0 = *(const uint4*)(gw_base + k0 + 64);
    }
    #pragma unroll
    for (int s = 0; s < 2; ++s) {
      const bf16x8 afr = *(const bf16x8*)&hT[(w4 * 16 + l16) * HLD + s * 32 + quad * 8];
      const bf16x8 bfr = *(const bf16x8*)&wT[brow * HLD + s * 32 + quad * 8];
      acc0 = __builtin_amdgcn_mfma_f32_16x16x32_bf16(afr, bfr, acc0, 0, 0, 0);
    }
    __syncthreads();
  }

  // team1 -> red (hst overlay; all hst reads complete)
  if (team == 1) {
    *(f32x4*)&red[(w4 * 64 + lane) * 4] = acc0;
  }
  __syncthreads();

  // team0: sum + scatter to sm_g[(g*4+jc)*64 + b] (wst overlay)
  if (team == 0) {
    const f32x4 t1 = *(const f32x4*)&red[(w4 * 64 + lane) * 4];
    const f32x4 s0 = acc0 + t1;
    if (l16 < 12) {
      #pragma unroll
      for (int reg = 0; reg < 4; ++reg) {
        const int b = w4 * 16 + quad * 4 + reg;
        sm_g[l16 * 64 + b] = s0[reg];
      }
    }
  }
  __syncthreads();

  // gate math — one (j,b) pair per thread (R6-verified formula/order)
  if (tid < 256) {
    const float sr = sm_g[(0 * 4 + ej) * 64 + eb];
    const float sz = sm_g[(1 * 4 + ej) * 64 + eb];
    const float sn = sm_g[(2 * 4 + ej) * 64 + eb];
    const float xr = bf2f(xrb), xz = bf2f(xzb), xn = bf2f(xnb);
    const float r = 1.f / (1.f + expf(-(xr + sr + bh_r)));
    const float z = 1.f / (1.f + expf(-(xz + sz + bh_z)));
    const float n = tanhf(xn + r * (sn + bh_n));
    const float hnew = (1.f - z) * n + z * hp;
    h_f[eb * HM_ + jje] = hnew;
    const bf16_t hb = f2bf(hnew);
    h_bf_out[eb * HM_ + jje] = hb;
    hs_c[(size_t)(eb * TC_ + tt) * HM_ + jje] = hb;
  }
}

// ---------------------------------------------------------------------------
// L1 GEMM with gathered rows (K=24, fp32 vector), bf16 output. (R5-proven)
// ---------------------------------------------------------------------------
#define BM 64
#define BN 64
#define BKK 16

__global__ __launch_bounds__(256) void gemm_l1_gather(
    const float* __restrict__ x, const float* __restrict__ W,
    const float* __restrict__ bias, bf16_t* __restrict__ C, int t0)
{
  __shared__ float As[BKK][BM];
  __shared__ float Ws[BKK][BN];
  const int tid = threadIdx.x;
  const int m0 = blockIdx.x * BM;
  const int n0 = blockIdx.y * BN;
  const int lr = tid >> 2;
  const int kq = (tid & 3) << 2;
  const int ty = tid >> 4;
  const int tx = tid & 15;
  const int r = m0 + lr;
  const int b = r / TC_;
  const int tt = r - b * TC_;
  const size_t srow = (size_t)b * T_ + t0 + tt;
  float acc[4][4] = {};
  for (int k0 = 0; k0 < IN_; k0 += BKK) {
    {
      float v0 = 0.f, v1 = 0.f, v2 = 0.f, v3 = 0.f;
      const int kk = k0 + kq;
      const float* src = x + srow * IN_ + kk;
      if (kk + 4 <= IN_) {
        const float4 v = *(const float4*)src;
        v0 = v.x; v1 = v.y; v2 = v.z; v3 = v.w;
      }
      As[kq + 0][lr] = v0; As[kq + 1][lr] = v1;
      As[kq + 2][lr] = v2; As[kq + 3][lr] = v3;
      float w0 = 0.f, w1 = 0.f, w2 = 0.f, w3 = 0.f;
      const float* srcw = W + (size_t)(n0 + lr) * IN_ + kk;
      if (kk + 4 <= IN_) {
        const float4 w = *(const float4*)srcw;
        w0 = w.x; w1 = w.y; w2 = w.z; w3 = w.w;
      }
      Ws[kq + 0][lr] = w0; Ws[kq + 1][lr] = w1;
      Ws[kq + 2][lr] = w2; Ws[kq + 3][lr] = w3;
    }
    __syncthreads();
    #pragma unroll
    for (int k = 0; k < BKK; ++k) {
      const float4 av = *(const float4*)&As[k][ty << 2];
      const float4 bv = *(const float4*)&Ws[k][tx << 2];
      const float aa[4] = {av.x, av.y, av.z, av.w};
      const float bb[4] = {bv.x, bv.y, bv.z, bv.w};
      #pragma unroll
      for (int i = 0; i < 4; ++i)
        #pragma unroll
        for (int j = 0; j < 4; ++j)
          acc[i][j] = fmaf(aa[i], bb[j], acc[i][j]);
    }
    __syncthreads();
  }
  const float4 bvec = *(const float4*)&bias[n0 + (tx << 2)];
  const float bb[4] = {bvec.x, bvec.y, bvec.z, bvec.w};
  #pragma unroll
  for (int i = 0; i < 4; ++i) {
    ushort4_t ov;
    ov.x = f2bf(fmaxf(acc[i][0] + bb[0], 0.f));
    ov.y = f2bf(fmaxf(acc[i][1] + bb[1], 0.f));
    ov.z = f2bf(fmaxf(acc[i][2] + bb[2], 0.f));
    ov.w = f2bf(fmaxf(acc[i][3] + bb[3], 0.f));
    *(ushort4_t*)&C[(size_t)(m0 + (ty << 2) + i) * H1_ + n0 + (tx << 2)] = ov;
  }
}

// Heads for one chunk (outs bf16). (R5-proven)
__global__ __launch_bounds__(256) void heads_kernel(
    const bf16_t* __restrict__ outs_c, const int* __restrict__ label,
    const float* __restrict__ W4, const float* __restrict__ b4,
    const float* __restrict__ W5, const float* __restrict__ b5,
    const float* __restrict__ W6, const float* __restrict__ b6,
    float* __restrict__ out, int t0)
{
  const int r = blockIdx.x;
  const int b = r / TC_;
  const int tt = r - b * TC_;
  int lab = label[b];
  lab = lab < 0 ? 0 : (lab > C_ - 1 ? C_ - 1 : lab);
  const int tid = threadIdx.x;
  const bf16_t* o = outs_c + (size_t)r * PEN_;
  const float* w4 = W4 + (size_t)lab * PEN_;
  const float* w5 = W5 + (size_t)lab * PEN_;
  const float* w6 = W6 + (size_t)lab * PEN_;
  float s4 = 0.f, s5 = 0.f, s6 = 0.f;
  for (int p = tid; p < PEN_; p += 256) {
    const float ov = bf2f(o[p]);
    s4 = fmaf(ov, w4[p], s4);
    s5 = fmaf(ov, w5[p], s5);
    s6 = fmaf(ov, w6[p], s6);
  }
  #pragma unroll
  for (int off = 32; off > 0; off >>= 1) {
    s4 += __shfl_down(s4, off, 64);
    s5 += __shfl_down(s5, off, 64);
    s6 += __shfl_down(s6, off, 64);
  }
  __shared__ float red[4][3];
  const int wave = tid >> 6;
  if ((tid & 63) == 0) { red[wave][0] = s4; red[wave][1] = s5; red[wave][2] = s6; }
  __syncthreads();
  if (tid == 0) {
    const int bt = b * T_ + t0 + tt;
    out[bt]           = red[0][0] + red[1][0] + red[2][0] + red[3][0] + b4[lab];
    out[BT_ + bt]     = red[0][1] + red[1][1] + red[2][1] + red[3][1] + b5[lab];
    out[2 * BT_ + bt] = red[0][2] + red[1][2] + red[2][2] + red[3][2] + b6[lab];
    if (t0 == 0 && r == 0) { out[3 * BT_] = 0.f; out[3 * BT_ + 1] = 0.f; }
  }
}

__global__ __launch_bounds__(256) void cvt_bf(const float* __restrict__ src,
                                              bf16_t* __restrict__ dst, int n) {
  const int i = (blockIdx.x * 256 + threadIdx.x) * 4;
  if (i + 4 <= n) {
    const float4 v = *(const float4*)&src[i];
    ushort4_t o = {f2bf(v.x), f2bf(v.y), f2bf(v.z), f2bf(v.w)};
    *(ushort4_t*)&dst[i] = o;
  }
}

__global__ __launch_bounds__(256) void zero_h(float* __restrict__ hf,
                                              bf16_t* __restrict__ hb0,
                                              bf16_t* __restrict__ hb1) {
  const int i = blockIdx.x * 256 + threadIdx.x;  // 131072
  hf[i] = 0.f; hb0[i] = 0; hb1[i] = 0;
}

extern "C" void kernel_launch(void* const* d_in, const int* in_sizes, int n_in,
                              void* d_out, int out_size, void* d_ws, size_t ws_size,
                              hipStream_t stream) {
  const float* x     = (const float*)d_in[0];
  const int*   label = (const int*)d_in[1];
  const float* W1    = (const float*)d_in[2];
  const float* b1    = (const float*)d_in[3];
  const float* W2    = (const float*)d_in[4];
  const float* b2    = (const float*)d_in[5];
  const float* W_ih  = (const float*)d_in[6];
  const float* W_hh  = (const float*)d_in[7];
  const float* b_ih  = (const float*)d_in[8];
  const float* b_hh  = (const float*)d_in[9];
  const float* W3    = (const float*)d_in[10];
  const float* b3    = (const float*)d_in[11];
  const float* W4    = (const float*)d_in[12];
  const float* b4    = (const float*)d_in[13];
  const float* W5    = (const float*)d_in[14];
  const float* b5    = (const float*)d_in[15];
  const float* W6    = (const float*)d_in[16];
  const float* b6    = (const float*)d_in[17];

  // Workspace layout (bytes). Base = 98,172,928 (proven).
  // bf16-weight extension (+33,554,432) used only if ws_size permits.
  const size_t NEEDED  = 98172928UL;
  const size_t NEEDED2 = 131727360UL;
  if (ws_size < NEEDED) return;
  const int use_bf = (ws_size >= NEEDED2);

  char* ws = (char*)d_ws;
  bf16_t* xg_c   = (bf16_t*)(ws + 0);
  bf16_t* out2_c = (bf16_t*)(ws + 47972352UL);
  bf16_t* hs_c   = out2_c;
  bf16_t* out1_c = (bf16_t*)(ws + 63963136UL);
  bf16_t* outs_c = out1_c;
  bf16_t* Whh_bf = (bf16_t*)(ws + 71958528UL);
  float*  h_f    = (float*)(ws + 97124352UL);
  bf16_t* hbuf[2];
  hbuf[0] = (bf16_t*)(ws + 97648640UL);
  hbuf[1] = (bf16_t*)(ws + 97910784UL);
  bf16_t* W2b  = (bf16_t*)(ws + 98172928UL);   // 4,194,304 B
  bf16_t* Wihb = (bf16_t*)(ws + 102367232UL);  // 25,165,824 B
  bf16_t* W3b  = (bf16_t*)(ws + 127533056UL);  // 4,194,304 B
  float* out = (float*)d_out;

  const dim3 blk(256);

  cvt_bf<<<dim3(G3_ * HM_ / 1024), blk, 0, stream>>>(W_hh, Whh_bf, G3_ * HM_);
  zero_h<<<dim3(B_ * HM_ / 256), blk, 0, stream>>>(h_f, hbuf[0], hbuf[1]);
  if (use_bf) {
    cvt_bf<<<dim3(H2_ * H1_ / 1024), blk, 0, stream>>>(W2, W2b, H2_ * H1_);
    cvt_bf<<<dim3(G3_ * H2_ / 1024), blk, 0, stream>>>(W_ih, Wihb, G3_ * H2_);
    cvt_bf<<<dim3(PEN_ * HM_ / 1024), blk, 0, stream>>>(W3, W3b, PEN_ * HM_);
  }

  int pp = 0;
  for (int c = 0; c < NCH; ++c) {
    const int t0 = c * TC_;
    gemm_l1_gather<<<dim3(MC / BM, H1_ / BN), blk, 0, stream>>>(x, W1, b1, out1_c, t0);
    if (use_bf) {
      gemm_mfma<1><<<dim3((MC + GBM - 1) / GBM, H2_ / GBN), blk, 0, stream>>>(
          out1_c, nullptr, W2b, b2, out2_c, MC, H2_, H1_, 1);
      gemm_mfma<1><<<dim3((MC + GBM - 1) / GBM, G3_ / GBN), blk, 0, stream>>>(
          out2_c, nullptr, Wihb, b_ih, xg_c, MC, G3_, H2_, 0);
    } else {
      gemm_mfma<0><<<dim3((MC + GBM - 1) / GBM, H2_ / GBN), blk, 0, stream>>>(
          out1_c, W2, nullptr, b2, out2_c, MC, H2_, H1_, 1);
      gemm_mfma<0><<<dim3((MC + GBM - 1) / GBM, G3_ / GBN), blk, 0, stream>>>(
          out2_c, W_ih, nullptr, b_ih, xg_c, MC, G3_, H2_, 0);
    }

    for (int tt = 0; tt < TC_; ++tt) {
      gru_step<<<dim3(HM_ / 4), dim3(512), 0, stream>>>(
          hbuf[pp], h_f, Whh_bf, xg_c, b_hh, hbuf[1 - pp], hs_c, tt);
      pp ^= 1;
    }

    if (use_bf) {
      gemm_mfma<1><<<dim3((MC + GBM - 1) / GBM, PEN_ / GBN), blk, 0, stream>>>(
          hs_c, nullptr, W3b, b3, outs_c, MC, PEN_, HM_, 1);
    } else {
      gemm_mfma<0><<<dim3((MC + GBM - 1) / GBM, PEN_ / GBN), blk, 0, stream>>>(
          hs_c, W3, nullptr, b3, outs_c, MC, PEN_, HM_, 1);
    }
    heads_kernel<<<dim3(MC), blk, 0, stream>>>(
        outs_c, label, W4, b4, W5, b5, W6, b6, out, t0);
  }
}

// Round 9
// 5747.640 us; speedup vs baseline: 1.2180x; 1.2180x over previous
//
#include <hip/hip_runtime.h>
#include <math.h>

#define B_   64
#define T_   366
#define IN_  24
#define H1_  1024
#define H2_  2048
#define HM_  2048
#define G3_  (3 * HM_)
#define PEN_ 1024
#define C_   21
#define BT_  (B_ * T_)

#define TC_  61              // T-chunk length (366 = 6*61)
#define NCH  6
#define MC   (B_ * TC_)      // 3904 rows per chunk

typedef unsigned short bf16_t;
typedef __bf16 bf16x8 __attribute__((ext_vector_type(8)));
typedef float  f32x4  __attribute__((ext_vector_type(4)));

__device__ __forceinline__ float bf2f(bf16_t u) {
  return __uint_as_float(((unsigned int)u) << 16);
}
__device__ __forceinline__ bf16_t f2bf(float f) {
  unsigned int x = __float_as_uint(f);
  unsigned int r = (x + 0x7fffu + ((x >> 16) & 1u)) >> 16;
  return (bf16_t)r;
}

struct ushort4_t { bf16_t x, y, z, w; };

#define AS1 __attribute__((address_space(1)))
#define AS3 __attribute__((address_space(3)))

// ---------------------------------------------------------------------------
// MFMA bf16 GEMM: C = act(A@W^T+b).  (R2-proven, unchanged)
// ---------------------------------------------------------------------------
#define GBM 128
#define GBN 128
#define GBK 32
#define LDT 40

template<int WBF>
__global__ __launch_bounds__(256) void gemm_mfma(
    const bf16_t* __restrict__ A, const float* __restrict__ Wf,
    const bf16_t* __restrict__ Wb,
    const float* __restrict__ bias, bf16_t* __restrict__ C,
    int M, int N, int K, int relu)
{
  __shared__ bf16_t Asl[GBM * LDT];
  __shared__ bf16_t Wsl[GBN * LDT];
  const int tid  = threadIdx.x;
  const int m0   = blockIdx.x * GBM;
  const int n0   = blockIdx.y * GBN;
  const int wave = tid >> 6;
  const int lane = tid & 63;
  const int l16  = lane & 15;
  const int quad = lane >> 4;
  const int wm   = (wave & 1) * 64;
  const int wn   = (wave >> 1) * 64;

  f32x4 acc[4][4];
  #pragma unroll
  for (int i = 0; i < 4; ++i)
    #pragma unroll
    for (int j = 0; j < 4; ++j)
      acc[i][j] = (f32x4){0.f, 0.f, 0.f, 0.f};

  if (WBF) {
    const int r4 = lane >> 2;
    const int sg = (lane & 3) << 3;    // bf16 elems: 0,8,16,24
    for (int k0 = 0; k0 < K; k0 += GBK) {
      #pragma unroll
      for (int it = 0; it < 2; ++it) {
        const int row = wave * 32 + it * 16 + r4;
        const int ar  = (m0 + row < M) ? (m0 + row) : (M - 1);
        __builtin_amdgcn_global_load_lds(
            (const AS1 void*)(A + (size_t)ar * K + k0 + sg),
            (AS3 void*)&Asl[(wave * 2 + it) * 512], 16, 0, 0);
        __builtin_amdgcn_global_load_lds(
            (const AS1 void*)(Wb + (size_t)(n0 + row) * K + k0 + sg),
            (AS3 void*)&Wsl[(wave * 2 + it) * 512], 16, 0, 0);
      }
      __syncthreads();
      bf16x8 af[4], bfr[4];
      #pragma unroll
      for (int i = 0; i < 4; ++i)
        af[i] = *(const bf16x8*)&Asl[(wm + 16 * i + l16) * 32 + quad * 8];
      #pragma unroll
      for (int j = 0; j < 4; ++j)
        bfr[j] = *(const bf16x8*)&Wsl[(wn + 16 * j + l16) * 32 + quad * 8];
      #pragma unroll
      for (int i = 0; i < 4; ++i)
        #pragma unroll
        for (int j = 0; j < 4; ++j)
          acc[i][j] = __builtin_amdgcn_mfma_f32_16x16x32_bf16(af[i], bfr[j], acc[i][j], 0, 0, 0);
      __syncthreads();
    }
  } else {
    const int srow = tid >> 1;
    const int sseg = (tid & 1) << 4;
    const int arow = (m0 + srow < M) ? (m0 + srow) : (M - 1);
    for (int k0 = 0; k0 < K; k0 += GBK) {
      {
        const bf16_t* ga = A + (size_t)arow * K + k0 + sseg;
        const uint4 a0 = *(const uint4*)ga;
        const uint4 a1 = *(const uint4*)(ga + 8);
        *(uint4*)&Asl[srow * LDT + sseg]     = a0;
        *(uint4*)&Asl[srow * LDT + sseg + 8] = a1;
        const float* gw = Wf + (size_t)(n0 + srow) * K + k0 + sseg;
        const float4 w0 = *(const float4*)gw;
        const float4 w1 = *(const float4*)(gw + 4);
        const float4 w2 = *(const float4*)(gw + 8);
        const float4 w3 = *(const float4*)(gw + 12);
        ushort4_t p0 = {f2bf(w0.x), f2bf(w0.y), f2bf(w0.z), f2bf(w0.w)};
        ushort4_t p1 = {f2bf(w1.x), f2bf(w1.y), f2bf(w1.z), f2bf(w1.w)};
        ushort4_t p2 = {f2bf(w2.x), f2bf(w2.y), f2bf(w2.z), f2bf(w2.w)};
        ushort4_t p3 = {f2bf(w3.x), f2bf(w3.y), f2bf(w3.z), f2bf(w3.w)};
        *(ushort4_t*)&Wsl[srow * LDT + sseg]      = p0;
        *(ushort4_t*)&Wsl[srow * LDT + sseg + 4]  = p1;
        *(ushort4_t*)&Wsl[srow * LDT + sseg + 8]  = p2;
        *(ushort4_t*)&Wsl[srow * LDT + sseg + 12] = p3;
      }
      __syncthreads();
      bf16x8 af[4], bfr[4];
      #pragma unroll
      for (int i = 0; i < 4; ++i)
        af[i] = *(const bf16x8*)&Asl[(wm + 16 * i + l16) * LDT + quad * 8];
      #pragma unroll
      for (int j = 0; j < 4; ++j)
        bfr[j] = *(const bf16x8*)&Wsl[(wn + 16 * j + l16) * LDT + quad * 8];
      #pragma unroll
      for (int i = 0; i < 4; ++i)
        #pragma unroll
        for (int j = 0; j < 4; ++j)
          acc[i][j] = __builtin_amdgcn_mfma_f32_16x16x32_bf16(af[i], bfr[j], acc[i][j], 0, 0, 0);
      __syncthreads();
    }
  }

  #pragma unroll
  for (int j = 0; j < 4; ++j) {
    const int n = n0 + wn + 16 * j + l16;
    const float bn = bias[n];
    #pragma unroll
    for (int i = 0; i < 4; ++i) {
      #pragma unroll
      for (int reg = 0; reg < 4; ++reg) {
        const int m = m0 + wm + 16 * i + quad * 4 + reg;
        if (m < M) {
          float v = acc[i][j][reg] + bn;
          if (relu) v = fmaxf(v, 0.f);
          C[(size_t)m * N + n] = f2bf(v);
        }
      }
    }
  }
}

// ---------------------------------------------------------------------------
// GRU step v8 — R6-proven kernel (256 wgs x 512 thr, 8 j-cols/wg, gate-packed
// B tiles, verified reduce/epilogue) with ONE change: DEPTH-2 register
// pipeline for the h/W staging loads (tile k+2 issued during phase k).
// Rationale: h is scattered across all 8 XCDs' L2s each step -> h loads are
// ~600-900 cyc; a phase is ~300 cyc, so depth-1 prefetch (R1/R3/R5/R6) left
// ~400+ cyc exposed per phase. Depth-2 gives 2 phases of cover. Identical
// MFMA order -> bit-identical numerics.
// ---------------------------------------------------------------------------
#define HLD 72   // padded LDS stride for 64-k tiles

__global__ __launch_bounds__(512) void gru_step(
    const bf16_t* __restrict__ h_bf_in, float* __restrict__ h_f,
    const bf16_t* __restrict__ Whh_bf, const bf16_t* __restrict__ xg_c,
    const float* __restrict__ b_hh,
    bf16_t* __restrict__ h_bf_out, bf16_t* __restrict__ hs_c, int tt)
{
  // hst: 2 teams x 64 x HLD x 2B = 18,432 B ; wst: 2 x 24 x HLD x 2B = 6,912 B
  // overlays after K-loop: red (8,192 B on hst) ; sm_g 3x8x64 f32 (6,144 B on wst)
  __shared__ char smem[25344];
  bf16_t* hst = (bf16_t*)smem;
  bf16_t* wst = (bf16_t*)(smem + 18432);
  float*  red = (float*)smem;                // [w4][tile][lane][4] f32 (team1)
  float*  sm_g = (float*)(smem + 18432);     // [g][jj][b] f32

  const int tid  = threadIdx.x;
  const int team = tid >> 8;           // K-half
  const int ttid = tid & 255;
  const int w4   = (tid >> 6) & 3;     // wave within team (= row-tile owner)
  const int lane = tid & 63;
  const int l16  = lane & 15;
  const int quad = lane >> 4;
  const int j0   = blockIdx.x * 8;
  const int kbase = team * (HM_ / 2);

  f32x4 acc0 = (f32x4){0.f, 0.f, 0.f, 0.f};  // tile0: g0 (l16<8) / g1 (l16>=8)
  f32x4 acc1 = acc0;                          // tile1: g2 (l16<8)

  // h staging: 64 rows, 4 thr/row, 32 B each (R6-proven mapping)
  const int hrow = ttid >> 2;
  const int hseg = (ttid & 3) << 4;
  // W staging: 24 rows (g*8+jj), 8 thr/row, 16 B each
  const int wrow = ttid >> 3;          // 0..23 valid for ttid<192
  const int wgi  = wrow >> 3;          // gate
  const int wjr  = wrow & 7;
  const int wseg = (ttid & 7) << 3;    // elems 0..56

  const bf16_t* gh_base = h_bf_in + (size_t)hrow * HM_ + kbase + hseg;
  const bf16_t* gw_base = Whh_bf + (size_t)(wgi * HM_ + j0 + wjr) * HM_ + kbase + wseg;

  // epilogue operand prefetch — ALL 512 threads, one (j,b) pair each
  // (R2/R6-verified mapping)
  const int ej  = tid & 7;
  const int eb  = tid >> 3;            // 0..63
  const int jje = j0 + ej;
  const size_t xrow = (size_t)(eb * TC_ + tt) * G3_;
  const bf16_t xrb = xg_c[xrow + jje];
  const bf16_t xzb = xg_c[xrow + HM_ + jje];
  const bf16_t xnb = xg_c[xrow + 2 * HM_ + jje];
  const float  hp  = h_f[eb * HM_ + jje];
  const float bh_r = b_hh[jje];
  const float bh_z = b_hh[HM_ + jje];
  const float bh_n = b_hh[2 * HM_ + jje];

  // depth-2 pipeline: preload k-tiles 0 and 1
  uint4 hA0 = *(const uint4*)(gh_base);
  uint4 hA1 = *(const uint4*)(gh_base + 8);
  uint4 hB0 = *(const uint4*)(gh_base + 64);
  uint4 hB1 = *(const uint4*)(gh_base + 64 + 8);
  uint4 wA = {0u,0u,0u,0u}, wB = {0u,0u,0u,0u};
  if (ttid < 192) {
    wA = *(const uint4*)(gw_base);
    wB = *(const uint4*)(gw_base + 64);
  }

  bf16_t* hT = hst + team * (64 * HLD);
  bf16_t* wT = wst + team * (24 * HLD);

  for (int k0 = 0; k0 < HM_ / 2; k0 += 64) {
    // stage tile k (regs A) -> LDS
    *(uint4*)&hT[hrow * HLD + hseg]     = hA0;
    *(uint4*)&hT[hrow * HLD + hseg + 8] = hA1;
    if (ttid < 192) *(uint4*)&wT[wrow * HLD + wseg] = wA;
    __syncthreads();
    // shift pipeline; issue tile k+2's loads (2 phases of latency cover)
    hA0 = hB0; hA1 = hB1; wA = wB;
    if (k0 + 128 < HM_ / 2) {
      hB0 = *(const uint4*)(gh_base + k0 + 128);
      hB1 = *(const uint4*)(gh_base + k0 + 128 + 8);
      if (ttid < 192) wB = *(const uint4*)(gw_base + k0 + 128);
    }
    #pragma unroll
    for (int s = 0; s < 2; ++s) {
      const bf16x8 afr = *(const bf16x8*)&hT[(w4 * 16 + l16) * HLD + s * 32 + quad * 8];
      const bf16x8 b0t = *(const bf16x8*)&wT[l16 * HLD + s * 32 + quad * 8];
      const bf16x8 b1t = *(const bf16x8*)&wT[(16 + (l16 & 7)) * HLD + s * 32 + quad * 8];
      acc0 = __builtin_amdgcn_mfma_f32_16x16x32_bf16(afr, b0t, acc0, 0, 0, 0);
      acc1 = __builtin_amdgcn_mfma_f32_16x16x32_bf16(afr, b1t, acc1, 0, 0, 0);
    }
    __syncthreads();
  }

  // team1 -> red (hst overlay; all hst reads complete)
  if (team == 1) {
    *(f32x4*)&red[((w4 * 2 + 0) * 64 + lane) * 4] = acc0;
    *(f32x4*)&red[((w4 * 2 + 1) * 64 + lane) * 4] = acc1;
  }
  __syncthreads();

  // team0: sum + scatter to sm_g[g][jj][b] (wst overlay; wst reads complete)
  if (team == 0) {
    const f32x4 t1a = *(const f32x4*)&red[((w4 * 2 + 0) * 64 + lane) * 4];
    const f32x4 t1b = *(const f32x4*)&red[((w4 * 2 + 1) * 64 + lane) * 4];
    const f32x4 s0 = acc0 + t1a;
    const f32x4 s1 = acc1 + t1b;
    const int ga = (l16 < 8) ? 0 : 1;
    const int jja = l16 & 7;
    #pragma unroll
    for (int reg = 0; reg < 4; ++reg) {
      const int b = w4 * 16 + quad * 4 + reg;
      sm_g[(ga * 8 + jja) * 64 + b] = s0[reg];
      if (l16 < 8) sm_g[(2 * 8 + l16) * 64 + b] = s1[reg];
    }
  }
  __syncthreads();

  // gate math — one (j,b) pair per thread (R2/R6-verified formula/order)
  {
    const float sr = sm_g[(0 * 8 + ej) * 64 + eb];
    const float sz = sm_g[(1 * 8 + ej) * 64 + eb];
    const float sn = sm_g[(2 * 8 + ej) * 64 + eb];
    const float xr = bf2f(xrb), xz = bf2f(xzb), xn = bf2f(xnb);
    const float r = 1.f / (1.f + expf(-(xr + sr + bh_r)));
    const float z = 1.f / (1.f + expf(-(xz + sz + bh_z)));
    const float n = tanhf(xn + r * (sn + bh_n));
    const float hnew = (1.f - z) * n + z * hp;
    h_f[eb * HM_ + jje] = hnew;
    const bf16_t hb = f2bf(hnew);
    h_bf_out[eb * HM_ + jje] = hb;
    hs_c[(size_t)(eb * TC_ + tt) * HM_ + jje] = hb;
  }
}

// ---------------------------------------------------------------------------
// L1 GEMM with gathered rows (K=24, fp32 vector), bf16 output. (R5-proven)
// ---------------------------------------------------------------------------
#define BM 64
#define BN 64
#define BKK 16

__global__ __launch_bounds__(256) void gemm_l1_gather(
    const float* __restrict__ x, const float* __restrict__ W,
    const float* __restrict__ bias, bf16_t* __restrict__ C, int t0)
{
  __shared__ float As[BKK][BM];
  __shared__ float Ws[BKK][BN];
  const int tid = threadIdx.x;
  const int m0 = blockIdx.x * BM;
  const int n0 = blockIdx.y * BN;
  const int lr = tid >> 2;
  const int kq = (tid & 3) << 2;
  const int ty = tid >> 4;
  const int tx = tid & 15;
  const int r = m0 + lr;
  const int b = r / TC_;
  const int tt = r - b * TC_;
  const size_t srow = (size_t)b * T_ + t0 + tt;
  float acc[4][4] = {};
  for (int k0 = 0; k0 < IN_; k0 += BKK) {
    {
      float v0 = 0.f, v1 = 0.f, v2 = 0.f, v3 = 0.f;
      const int kk = k0 + kq;
      const float* src = x + srow * IN_ + kk;
      if (kk + 4 <= IN_) {
        const float4 v = *(const float4*)src;
        v0 = v.x; v1 = v.y; v2 = v.z; v3 = v.w;
      }
      As[kq + 0][lr] = v0; As[kq + 1][lr] = v1;
      As[kq + 2][lr] = v2; As[kq + 3][lr] = v3;
      float w0 = 0.f, w1 = 0.f, w2 = 0.f, w3 = 0.f;
      const float* srcw = W + (size_t)(n0 + lr) * IN_ + kk;
      if (kk + 4 <= IN_) {
        const float4 w = *(const float4*)srcw;
        w0 = w.x; w1 = w.y; w2 = w.z; w3 = w.w;
      }
      Ws[kq + 0][lr] = w0; Ws[kq + 1][lr] = w1;
      Ws[kq + 2][lr] = w2; Ws[kq + 3][lr] = w3;
    }
    __syncthreads();
    #pragma unroll
    for (int k = 0; k < BKK; ++k) {
      const float4 av = *(const float4*)&As[k][ty << 2];
      const float4 bv = *(const float4*)&Ws[k][tx << 2];
      const float aa[4] = {av.x, av.y, av.z, av.w};
      const float bb[4] = {bv.x, bv.y, bv.z, bv.w};
      #pragma unroll
      for (int i = 0; i < 4; ++i)
        #pragma unroll
        for (int j = 0; j < 4; ++j)
          acc[i][j] = fmaf(aa[i], bb[j], acc[i][j]);
    }
    __syncthreads();
  }
  const float4 bvec = *(const float4*)&bias[n0 + (tx << 2)];
  const float bb[4] = {bvec.x, bvec.y, bvec.z, bvec.w};
  #pragma unroll
  for (int i = 0; i < 4; ++i) {
    ushort4_t ov;
    ov.x = f2bf(fmaxf(acc[i][0] + bb[0], 0.f));
    ov.y = f2bf(fmaxf(acc[i][1] + bb[1], 0.f));
    ov.z = f2bf(fmaxf(acc[i][2] + bb[2], 0.f));
    ov.w = f2bf(fmaxf(acc[i][3] + bb[3], 0.f));
    *(ushort4_t*)&C[(size_t)(m0 + (ty << 2) + i) * H1_ + n0 + (tx << 2)] = ov;
  }
}

// Heads for one chunk (outs bf16). (R5-proven)
__global__ __launch_bounds__(256) void heads_kernel(
    const bf16_t* __restrict__ outs_c, const int* __restrict__ label,
    const float* __restrict__ W4, const float* __restrict__ b4,
    const float* __restrict__ W5, const float* __restrict__ b5,
    const float* __restrict__ W6, const float* __restrict__ b6,
    float* __restrict__ out, int t0)
{
  const int r = blockIdx.x;
  const int b = r / TC_;
  const int tt = r - b * TC_;
  int lab = label[b];
  lab = lab < 0 ? 0 : (lab > C_ - 1 ? C_ - 1 : lab);
  const int tid = threadIdx.x;
  const bf16_t* o = outs_c + (size_t)r * PEN_;
  const float* w4 = W4 + (size_t)lab * PEN_;
  const float* w5 = W5 + (size_t)lab * PEN_;
  const float* w6 = W6 + (size_t)lab * PEN_;
  float s4 = 0.f, s5 = 0.f, s6 = 0.f;
  for (int p = tid; p < PEN_; p += 256) {
    const float ov = bf2f(o[p]);
    s4 = fmaf(ov, w4[p], s4);
    s5 = fmaf(ov, w5[p], s5);
    s6 = fmaf(ov, w6[p], s6);
  }
  #pragma unroll
  for (int off = 32; off > 0; off >>= 1) {
    s4 += __shfl_down(s4, off, 64);
    s5 += __shfl_down(s5, off, 64);
    s6 += __shfl_down(s6, off, 64);
  }
  __shared__ float red[4][3];
  const int wave = tid >> 6;
  if ((tid & 63) == 0) { red[wave][0] = s4; red[wave][1] = s5; red[wave][2] = s6; }
  __syncthreads();
  if (tid == 0) {
    const int bt = b * T_ + t0 + tt;
    out[bt]           = red[0][0] + red[1][0] + red[2][0] + red[3][0] + b4[lab];
    out[BT_ + bt]     = red[0][1] + red[1][1] + red[2][1] + red[3][1] + b5[lab];
    out[2 * BT_ + bt] = red[0][2] + red[1][2] + red[2][2] + red[3][2] + b6[lab];
    if (t0 == 0 && r == 0) { out[3 * BT_] = 0.f; out[3 * BT_ + 1] = 0.f; }
  }
}

__global__ __launch_bounds__(256) void cvt_bf(const float* __restrict__ src,
                                              bf16_t* __restrict__ dst, int n) {
  const int i = (blockIdx.x * 256 + threadIdx.x) * 4;
  if (i + 4 <= n) {
    const float4 v = *(const float4*)&src[i];
    ushort4_t o = {f2bf(v.x), f2bf(v.y), f2bf(v.z), f2bf(v.w)};
    *(ushort4_t*)&dst[i] = o;
  }
}

__global__ __launch_bounds__(256) void zero_h(float* __restrict__ hf,
                                              bf16_t* __restrict__ hb0,
                                              bf16_t* __restrict__ hb1) {
  const int i = blockIdx.x * 256 + threadIdx.x;  // 131072
  hf[i] = 0.f; hb0[i] = 0; hb1[i] = 0;
}

extern "C" void kernel_launch(void* const* d_in, const int* in_sizes, int n_in,
                              void* d_out, int out_size, void* d_ws, size_t ws_size,
                              hipStream_t stream) {
  const float* x     = (const float*)d_in[0];
  const int*   label = (const int*)d_in[1];
  const float* W1    = (const float*)d_in[2];
  const float* b1    = (const float*)d_in[3];
  const float* W2    = (const float*)d_in[4];
  const float* b2    = (const float*)d_in[5];
  const float* W_ih  = (const float*)d_in[6];
  const float* W_hh  = (const float*)d_in[7];
  const float* b_ih  = (const float*)d_in[8];
  const float* b_hh  = (const float*)d_in[9];
  const float* W3    = (const float*)d_in[10];
  const float* b3    = (const float*)d_in[11];
  const float* W4    = (const float*)d_in[12];
  const float* b4    = (const float*)d_in[13];
  const float* W5    = (const float*)d_in[14];
  const float* b5    = (const float*)d_in[15];
  const float* W6    = (const float*)d_in[16];
  const float* b6    = (const float*)d_in[17];

  // Workspace layout (bytes). Base = 98,172,928 (proven).
  // bf16-weight extension (+33,554,432) used only if ws_size permits.
  const size_t NEEDED  = 98172928UL;
  const size_t NEEDED2 = 131727360UL;
  if (ws_size < NEEDED) return;
  const int use_bf = (ws_size >= NEEDED2);

  char* ws = (char*)d_ws;
  bf16_t* xg_c   = (bf16_t*)(ws + 0);
  bf16_t* out2_c = (bf16_t*)(ws + 47972352UL);
  bf16_t* hs_c   = out2_c;
  bf16_t* out1_c = (bf16_t*)(ws + 63963136UL);
  bf16_t* outs_c = out1_c;
  bf16_t* Whh_bf = (bf16_t*)(ws + 71958528UL);
  float*  h_f    = (float*)(ws + 97124352UL);
  bf16_t* hbuf[2];
  hbuf[0] = (bf16_t*)(ws + 97648640UL);
  hbuf[1] = (bf16_t*)(ws + 97910784UL);
  bf16_t* W2b  = (bf16_t*)(ws + 98172928UL);   // 4,194,304 B
  bf16_t* Wihb = (bf16_t*)(ws + 102367232UL);  // 25,165,824 B
  bf16_t* W3b  = (bf16_t*)(ws + 127533056UL);  // 4,194,304 B
  float* out = (float*)d_out;

  const dim3 blk(256);

  cvt_bf<<<dim3(G3_ * HM_ / 1024), blk, 0, stream>>>(W_hh, Whh_bf, G3_ * HM_);
  zero_h<<<dim3(B_ * HM_ / 256), blk, 0, stream>>>(h_f, hbuf[0], hbuf[1]);
  if (use_bf) {
    cvt_bf<<<dim3(H2_ * H1_ / 1024), blk, 0, stream>>>(W2, W2b, H2_ * H1_);
    cvt_bf<<<dim3(G3_ * H2_ / 1024), blk, 0, stream>>>(W_ih, Wihb, G3_ * H2_);
    cvt_bf<<<dim3(PEN_ * HM_ / 1024), blk, 0, stream>>>(W3, W3b, PEN_ * HM_);
  }

  int pp = 0;
  for (int c = 0; c < NCH; ++c) {
    const int t0 = c * TC_;
    gemm_l1_gather<<<dim3(MC / BM, H1_ / BN), blk, 0, stream>>>(x, W1, b1, out1_c, t0);
    if (use_bf) {
      gemm_mfma<1><<<dim3((MC + GBM - 1) / GBM, H2_ / GBN), blk, 0, stream>>>(
          out1_c, nullptr, W2b, b2, out2_c, MC, H2_, H1_, 1);
      gemm_mfma<1><<<dim3((MC + GBM - 1) / GBM, G3_ / GBN), blk, 0, stream>>>(
          out2_c, nullptr, Wihb, b_ih, xg_c, MC, G3_, H2_, 0);
    } else {
      gemm_mfma<0><<<dim3((MC + GBM - 1) / GBM, H2_ / GBN), blk, 0, stream>>>(
          out1_c, W2, nullptr, b2, out2_c, MC, H2_, H1_, 1);
      gemm_mfma<0><<<dim3((MC + GBM - 1) / GBM, G3_ / GBN), blk, 0, stream>>>(
          out2_c, W_ih, nullptr, b_ih, xg_c, MC, G3_, H2_, 0);
    }

    for (int tt = 0; tt < TC_; ++tt) {
      gru_step<<<dim3(HM_ / 8), dim3(512), 0, stream>>>(
          hbuf[pp], h_f, Whh_bf, xg_c, b_hh, hbuf[1 - pp], hs_c, tt);
      pp ^= 1;
    }

    if (use_bf) {
      gemm_mfma<1><<<dim3((MC + GBM - 1) / GBM, PEN_ / GBN), blk, 0, stream>>>(
          hs_c, nullptr, W3b, b3, outs_c, MC, PEN_, HM_, 1);
    } else {
      gemm_mfma<0><<<dim3((MC + GBM - 1) / GBM, PEN_ / GBN), blk, 0, stream>>>(
          hs_c, W3, nullptr, b3, outs_c, MC, PEN_, HM_, 1);
    }
    heads_kernel<<<dim3(MC), blk, 0, stream>>>(
        outs_c, label, W4, b4, W5, b5, W6, b6, out, t0);
  }
}